// Round 3
// baseline (15106.487 us; speedup 1.0000x reference)
//
#include <hip/hip_runtime.h>
#include <stdint.h>

#define B_  32
#define T_  1024
#define I_  512
#define H_  1024
#define C_  512
#define G4H 4096
#define NWG 128

typedef __bf16 bf16x8 __attribute__((ext_vector_type(8)));
typedef float  f32x4  __attribute__((ext_vector_type(4)));
typedef unsigned long long u64;

__device__ __forceinline__ unsigned short f2bf(float f) {
    uint32_t b = __float_as_uint(f);
    b = (b + 0x7FFFu + ((b >> 16) & 1u)) >> 16;
    return (unsigned short)b;
}
__device__ __forceinline__ float sigf(float x)   { return 1.0f / (1.0f + __expf(-x)); }
__device__ __forceinline__ float tanh_f(float x) { return 2.0f / (1.0f + __expf(-2.0f * x)) - 1.0f; }

// ---------------- fp32 -> bf16 conversion (vectorized x4) ----------------
__global__ void cvt_kernel(const float* __restrict__ src, unsigned short* __restrict__ dst, int n4) {
    int i = blockIdx.x * blockDim.x + threadIdx.x;
    if (i < n4) {
        float4 v = ((const float4*)src)[i];
        ushort4 o;
        o.x = f2bf(v.x); o.y = f2bf(v.y); o.z = f2bf(v.z); o.w = f2bf(v.w);
        ((ushort4*)dst)[i] = o;
    }
}

// x: [B][T][I] fp32 -> [T][B][I] bf16 (per-step slice contiguous 32KB)
__global__ void cvt_x_kernel(const float* __restrict__ src, unsigned short* __restrict__ dst) {
    int i4 = blockIdx.x * blockDim.x + threadIdx.x;       // over B*T*I/4
    int b   = i4 / (T_ * I_ / 4);
    int rem = i4 % (T_ * I_ / 4);
    int t   = rem / (I_ / 4);
    int c4  = rem % (I_ / 4);
    float4 v = ((const float4*)src)[i4];
    ushort4 o;
    o.x = f2bf(v.x); o.y = f2bf(v.y); o.z = f2bf(v.z); o.w = f2bf(v.w);
    ((ushort4*)dst)[(t * B_ + b) * (I_ / 4) + c4] = o;
}

__global__ void bias_kernel(const float* __restrict__ a, const float* __restrict__ b, float* __restrict__ o) {
    int i = blockIdx.x * blockDim.x + threadIdx.x;
    if (i < G4H) o[i] = a[i] + b[i];
}

// ---------------- persistent LSTM recurrence, per-wave dataflow sync ----------------
// 128 WGs x 512 threads. WG wg owns hidden units [wg*8, wg*8+8) -> 32 gate cols.
// LDS W slice [32 cols][1536 K] bf16, XOR-swizzled by 16B granule (g ^ (col&7)).
// Wave wq: x-K [wq*64,+64), h-K [wq*128,+128). Partials reduced via ds_add_f32
// into bank-swizzled scratch[par][32b][32c] (col ^ ((bb&7)<<2)), double-buffered
// by step parity; pointwise threads re-zero the slots they read.
// Publish: pointwise waves 0-3 stage h in wave-private LDS, 16x8B agent stores,
// vmcnt(0), then per-wave flag flags[t+1][wg][w]. Consumers: wave wq polls the
// 64 flags (producers wq*16..+16, waves 0-4) = flags + t*512 + wq*64 + lane.
__global__ __launch_bounds__(512, 1) void lstm_rec(
        const unsigned short* __restrict__ whh,   // [4096][1024] bf16
        const unsigned short* __restrict__ wih,   // [4096][512]  bf16
        const unsigned short* __restrict__ xb,    // [1024][32][512] bf16
        const float* __restrict__ bias,           // [4096] (b_ih + b_hh)
        unsigned short* __restrict__ hall,        // [1025][32][1024] bf16 (slot 0 pre-zeroed)
        unsigned int* __restrict__ flags)         // [1025][128][4] (pre-zeroed)
{
    extern __shared__ char smem[];
    unsigned short* Wlds    = (unsigned short*)smem;                 // 98304 B
    float*          scratch = (float*)(smem + 98304);                // 2*1024 f32 = 8192 B
    float*          biasl   = (float*)(smem + 98304 + 8192);         // 128 B
    unsigned short* hstage  = (unsigned short*)(smem + 98304 + 8192 + 128); // 512 B

    const int tid  = threadIdx.x;
    const int wg   = blockIdx.x;
    const int lane = tid & 63;
    const int wq   = tid >> 6;
    const int l15  = lane & 15;
    const int l4   = lane >> 4;

    // ---- one-time: stage W slice into LDS (swizzled) ----
    for (int s = tid; s < 32 * 192; s += 512) {
        int col = s / 192, g = s % 192;
        int grow = (col >> 3) * H_ + wg * 8 + (col & 7);
        const unsigned short* src = (g < 128) ? (whh + grow * H_ + g * 8)
                                              : (wih + grow * I_ + (g - 128) * 8);
        int4 v = *(const int4*)src;
        int gd = g ^ (col & 7);
        *(int4*)(Wlds + col * 1536 + gd * 8) = v;
    }
    if (tid < 32)
        biasl[tid] = bias[(tid >> 3) * H_ + wg * 8 + (tid & 7)];
    for (int s = tid; s < 2048; s += 512) scratch[s] = 0.0f;
    __syncthreads();

    float c_state = 0.0f;

    for (int t = 0; t < T_; ++t) {
        float* scr = scratch + (t & 1) * 1024;

        f32x4 acc[2][2];
        #pragma unroll
        for (int a = 0; a < 2; a++)
            #pragma unroll
            for (int b = 0; b < 2; b++) acc[a][b] = (f32x4){0.f, 0.f, 0.f, 0.f};

        // ---- x-part first (no h dependency) ----
        #pragma unroll
        for (int kxs = 0; kxs < 2; kxs++) {
            int kk = wq * 64 + kxs * 32 + l4 * 8;
            bf16x8 af[2];
            #pragma unroll
            for (int mt = 0; mt < 2; mt++) {
                int bb = mt * 16 + l15;
                af[mt] = *(const bf16x8*)(xb + ((size_t)t * B_ + bb) * I_ + kk);
            }
            int gbase = 128 + (kk >> 3);
            bf16x8 bfr[2];
            #pragma unroll
            for (int nt = 0; nt < 2; nt++) {
                int col = nt * 16 + l15;
                int gg = gbase ^ (col & 7);
                bfr[nt] = *(const bf16x8*)(Wlds + col * 1536 + gg * 8);
            }
            #pragma unroll
            for (int mt = 0; mt < 2; mt++)
                #pragma unroll
                for (int nt = 0; nt < 2; nt++)
                    acc[mt][nt] = __builtin_amdgcn_mfma_f32_16x16x32_bf16(af[mt], bfr[nt], acc[mt][nt], 0, 0, 0);
        }

        // ---- per-wave wait: 64 flags covering this wave's h K-slice ----
        if (t > 0) {
            const unsigned int* fp = flags + (size_t)t * 512 + wq * 64 + lane;
            while (__hip_atomic_load(fp, __ATOMIC_RELAXED, __HIP_MEMORY_SCOPE_AGENT) == 0u) {}
        }

        // ---- h-part ----
        const unsigned short* hprev = hall + (size_t)t * (B_ * H_);
        #pragma unroll
        for (int khs = 0; khs < 4; khs++) {
            int kk = wq * 128 + khs * 32 + l4 * 8;
            bf16x8 af[2];
            #pragma unroll
            for (int mt = 0; mt < 2; mt++) {
                int bb = mt * 16 + l15;
                af[mt] = *(const bf16x8*)(hprev + bb * H_ + kk);
            }
            int gbase = kk >> 3;
            bf16x8 bfr[2];
            #pragma unroll
            for (int nt = 0; nt < 2; nt++) {
                int col = nt * 16 + l15;
                int gg = gbase ^ (col & 7);
                bfr[nt] = *(const bf16x8*)(Wlds + col * 1536 + gg * 8);
            }
            #pragma unroll
            for (int mt = 0; mt < 2; mt++)
                #pragma unroll
                for (int nt = 0; nt < 2; nt++)
                    acc[mt][nt] = __builtin_amdgcn_mfma_f32_16x16x32_bf16(af[mt], bfr[nt], acc[mt][nt], 0, 0, 0);
        }

        // ---- reduce partials via LDS f32 atomics (bank-swizzled) ----
        #pragma unroll
        for (int mt = 0; mt < 2; mt++)
            #pragma unroll
            for (int nt = 0; nt < 2; nt++)
                #pragma unroll
                for (int r = 0; r < 4; r++) {
                    int bb  = mt * 16 + l4 * 4 + r;
                    int col = nt * 16 + l15;
                    unsafeAtomicAdd(&scr[bb * 32 + (col ^ ((bb & 7) << 2))], acc[mt][nt][r]);
                }
        __syncthreads();

        // ---- pointwise + wave-local publish (waves 0-3, no further barriers) ----
        if (tid < 256) {
            int bb = tid >> 3, u = tid & 7;
            int sw = (bb & 7) << 2;
            float p0 = biasl[u]      + scr[bb * 32 + ((u)      ^ sw)];
            float p1 = biasl[8 + u]  + scr[bb * 32 + ((8 + u)  ^ sw)];
            float p2 = biasl[16 + u] + scr[bb * 32 + ((16 + u) ^ sw)];
            float p3 = biasl[24 + u] + scr[bb * 32 + ((24 + u) ^ sw)];
            // re-zero for reuse at t+2 (safe: flags all-gate-all each step)
            scr[bb * 32 + ((u)      ^ sw)] = 0.0f;
            scr[bb * 32 + ((8 + u)  ^ sw)] = 0.0f;
            scr[bb * 32 + ((16 + u) ^ sw)] = 0.0f;
            scr[bb * 32 + ((24 + u) ^ sw)] = 0.0f;
            float ig = sigf(p0), fg = sigf(p1), gg = tanh_f(p2), og = sigf(p3);
            c_state = fg * c_state + ig * gg;
            float h = og * tanh_f(c_state);
            hstage[bb * 8 + u] = f2bf(h);            // wave-private region

            int w = tid >> 6, i = tid & 63;
            if (i < 16) {
                int pb = w * 8 + (i >> 1), part = i & 1;
                u64 q = *(const u64*)(hstage + pb * 8 + part * 4);
                u64* dst = (u64*)(hall + ((size_t)(t + 1) * B_ + pb) * H_ + wg * 8 + part * 4);
                __hip_atomic_store(dst, q, __ATOMIC_RELAXED, __HIP_MEMORY_SCOPE_AGENT);
            }
            asm volatile("s_waitcnt vmcnt(0)" ::: "memory");
            if (i == 0)
                __hip_atomic_store(flags + (size_t)(t + 1) * 512 + wg * 4 + w, 1u,
                                   __ATOMIC_RELAXED, __HIP_MEMORY_SCOPE_AGENT);
        }
    }
}

// ---------------- output GEMMs: C[M x N] = A[M x 1024] * B[N x 1024]^T + bias ----------------
template<int PERM>
__global__ __launch_bounds__(256) void gemm_bt(
        const unsigned short* __restrict__ A,
        const unsigned short* __restrict__ Bw,
        const float* __restrict__ bias,
        float* __restrict__ out)
{
    __shared__ unsigned short As[128 * 64];
    __shared__ unsigned short Bs[128 * 64];
    const int tid  = threadIdx.x;
    const int lane = tid & 63, w = tid >> 6;
    const int wm = w >> 1, wn = w & 1;
    const int mbase = blockIdx.y * 128, nbase = blockIdx.x * 128;
    const int l15 = lane & 15, l4 = lane >> 4;

    f32x4 acc[4][4];
    #pragma unroll
    for (int i = 0; i < 4; i++)
        #pragma unroll
        for (int j = 0; j < 4; j++) acc[i][j] = (f32x4){0.f, 0.f, 0.f, 0.f};

    for (int kb = 0; kb < 16; kb++) {
        __syncthreads();
        #pragma unroll
        for (int i = 0; i < 4; i++) {
            int s = i * 256 + tid;
            int row = s >> 3, g = s & 7;
            int gd = g ^ (row & 7);
            int4 va = *(const int4*)(A  + (mbase + row) * 1024 + kb * 64 + g * 8);
            *(int4*)(As + row * 64 + gd * 8) = va;
            int4 vb = *(const int4*)(Bw + (nbase + row) * 1024 + kb * 64 + g * 8);
            *(int4*)(Bs + row * 64 + gd * 8) = vb;
        }
        __syncthreads();
        #pragma unroll
        for (int kk = 0; kk < 2; kk++) {
            bf16x8 af[4], bf[4];
            #pragma unroll
            for (int mt = 0; mt < 4; mt++) {
                int row = wm * 64 + mt * 16 + l15;
                int gg = (kk * 4 + l4) ^ (row & 7);
                af[mt] = *(const bf16x8*)(As + row * 64 + gg * 8);
            }
            #pragma unroll
            for (int nt = 0; nt < 4; nt++) {
                int row = wn * 64 + nt * 16 + l15;
                int gg = (kk * 4 + l4) ^ (row & 7);
                bf[nt] = *(const bf16x8*)(Bs + row * 64 + gg * 8);
            }
            #pragma unroll
            for (int mt = 0; mt < 4; mt++)
                #pragma unroll
                for (int nt = 0; nt < 4; nt++)
                    acc[mt][nt] = __builtin_amdgcn_mfma_f32_16x16x32_bf16(af[mt], bf[nt], acc[mt][nt], 0, 0, 0);
        }
    }
    #pragma unroll
    for (int mt = 0; mt < 4; mt++)
        #pragma unroll
        for (int nt = 0; nt < 4; nt++)
            #pragma unroll
            for (int r = 0; r < 4; r++) {
                int grow = mbase + wm * 64 + mt * 16 + l4 * 4 + r;
                int gcol = nbase + wn * 64 + nt * 16 + l15;
                float v = acc[mt][nt][r] + bias[gcol];
                int idx;
                if (PERM == 1) {
                    int tt = grow >> 5, bb = grow & 31;
                    idx = (bb * 1024 + tt) * 512 + gcol;
                } else {
                    idx = grow * 1024 + gcol;
                }
                out[idx] = v;
            }
}

// ---------------- host ----------------
extern "C" void kernel_launch(void* const* d_in, const int* in_sizes, int n_in,
                              void* d_out, int out_size, void* d_ws, size_t ws_size,
                              hipStream_t stream) {
    (void)in_sizes; (void)n_in; (void)out_size; (void)ws_size;
    const float* x    = (const float*)d_in[0];
    const float* Wih  = (const float*)d_in[1];
    const float* Whh  = (const float*)d_in[2];
    const float* bih  = (const float*)d_in[3];
    const float* bhh  = (const float*)d_in[4];
    const float* fcw  = (const float*)d_in[5];
    const float* fcb  = (const float*)d_in[6];
    const float* lnw  = (const float*)d_in[7];
    const float* lnb  = (const float*)d_in[8];
    float* out = (float*)d_out;

    char* ws = (char*)d_ws;
    size_t o = 0;
    unsigned short* whh_b = (unsigned short*)(ws + o); o += 8388608;   // [4096][1024]
    unsigned short* wih_b = (unsigned short*)(ws + o); o += 4194304;   // [4096][512]
    unsigned short* fcw_b = (unsigned short*)(ws + o); o += 1048576;   // [512][1024]
    unsigned short* lnw_b = (unsigned short*)(ws + o); o += 2097152;   // [1024][1024]
    unsigned short* x_b   = (unsigned short*)(ws + o); o += 33554432;  // [1024][32][512]
    float*          bias_c = (float*)(ws + o);         o += 16384;     // [4096]
    unsigned short* hall  = (unsigned short*)(ws + o); o += 67174400;  // [1025][32][1024]
    unsigned int*   flags = (unsigned int*)(ws + o);   o += 2099200;   // [1025][128][4]

    hipMemsetAsync(flags, 0, 2099200, stream);
    hipMemsetAsync(hall, 0, 65536, stream);      // h slot 0 = zeros

    cvt_kernel<<<4096,  256, 0, stream>>>(Whh, whh_b, 4194304 / 4);
    cvt_kernel<<<2048,  256, 0, stream>>>(Wih, wih_b, 2097152 / 4);
    cvt_kernel<<<512,   256, 0, stream>>>(fcw, fcw_b, 524288 / 4);
    cvt_kernel<<<1024,  256, 0, stream>>>(lnw, lnw_b, 1048576 / 4);
    cvt_x_kernel<<<16384, 256, 0, stream>>>(x, x_b);
    bias_kernel<<<16, 256, 0, stream>>>(bih, bhh, bias_c);

    const unsigned short* a0 = whh_b;
    const unsigned short* a1 = wih_b;
    const unsigned short* a2 = x_b;
    const float*          a3 = bias_c;
    unsigned short*       a4 = hall;
    unsigned int*         a5 = flags;
    void* args[6] = { (void*)&a0, (void*)&a1, (void*)&a2, (void*)&a3, (void*)&a4, (void*)&a5 };
    hipLaunchCooperativeKernel((void*)lstm_rec, dim3(NWG), dim3(512), args,
                               (unsigned)(98304 + 8192 + 128 + 512), stream);

    const unsigned short* hseq = hall + 32768;  // slot 1 = h at t=0
    gemm_bt<1><<<dim3(4, 256), 256, 0, stream>>>(hseq, fcw_b, fcb, out);
    gemm_bt<2><<<dim3(8, 256), 256, 0, stream>>>(hseq, lnw_b, lnb, out + 16777216);
}

// Round 4
// 6441.311 us; speedup vs baseline: 2.3453x; 2.3453x over previous
//
#include <hip/hip_runtime.h>
#include <stdint.h>

#define B_  32
#define T_  1024
#define I_  512
#define H_  1024
#define C_  512
#define G4H 4096
#define NWG 128

typedef __bf16 bf16x8 __attribute__((ext_vector_type(8)));
typedef float  f32x4  __attribute__((ext_vector_type(4)));
typedef unsigned long long u64;

__device__ __forceinline__ unsigned short f2bf(float f) {
    uint32_t b = __float_as_uint(f);
    b = (b + 0x7FFFu + ((b >> 16) & 1u)) >> 16;
    return (unsigned short)b;
}
__device__ __forceinline__ float sigf(float x)   { return 1.0f / (1.0f + __expf(-x)); }
__device__ __forceinline__ float tanh_f(float x) { return 2.0f / (1.0f + __expf(-2.0f * x)) - 1.0f; }

// ---------------- fp32 -> bf16 conversion (vectorized x4) ----------------
__global__ void cvt_kernel(const float* __restrict__ src, unsigned short* __restrict__ dst, int n4) {
    int i = blockIdx.x * blockDim.x + threadIdx.x;
    if (i < n4) {
        float4 v = ((const float4*)src)[i];
        ushort4 o;
        o.x = f2bf(v.x); o.y = f2bf(v.y); o.z = f2bf(v.z); o.w = f2bf(v.w);
        ((ushort4*)dst)[i] = o;
    }
}

// x: [B][T][I] fp32 -> [T][B][I] bf16 (per-step slice contiguous 32KB)
__global__ void cvt_x_kernel(const float* __restrict__ src, unsigned short* __restrict__ dst) {
    int i4 = blockIdx.x * blockDim.x + threadIdx.x;       // over B*T*I/4
    int b   = i4 / (T_ * I_ / 4);
    int rem = i4 % (T_ * I_ / 4);
    int t   = rem / (I_ / 4);
    int c4  = rem % (I_ / 4);
    float4 v = ((const float4*)src)[i4];
    ushort4 o;
    o.x = f2bf(v.x); o.y = f2bf(v.y); o.z = f2bf(v.z); o.w = f2bf(v.w);
    ((ushort4*)dst)[(t * B_ + b) * (I_ / 4) + c4] = o;
}

__global__ void bias_kernel(const float* __restrict__ a, const float* __restrict__ b, float* __restrict__ o) {
    int i = blockIdx.x * blockDim.x + threadIdx.x;
    if (i < G4H) o[i] = a[i] + b[i];
}

// ---------------- persistent LSTM recurrence ----------------
// 128 WGs x 512 threads. WG wg owns hidden units [wg*8, wg*8+8) -> 32 gate cols.
// LDS W slice [32 cols][1536 K] bf16, XOR-swizzled by 16B granule (g ^ (col&7)).
// Wave wq: x-K [wq*64,+64), h-K [wq*128,+128).
// Reduce: per-wave private scratch region (plain swizzled writes, <=2-way banks),
// ONE __syncthreads per step, then waves 0-3 do pointwise+publish while waves
// 4-7 run ahead into step t+1 (single-buffer scratch is WAR-safe: any write(t+1)
// is gated by flags(t+1), set only after pointwise finished reading scratch(t)).
// Publish: per-wave flag after vmcnt(0)-drained agent stores.
// Wait: per-wave poll of its 64 producer flags (32 lanes x u64, s_sleep backoff).
__global__ __launch_bounds__(512, 1) void lstm_rec(
        const unsigned short* __restrict__ whh,   // [4096][1024] bf16
        const unsigned short* __restrict__ wih,   // [4096][512]  bf16
        const unsigned short* __restrict__ xb,    // [1024][32][512] bf16
        const float* __restrict__ bias,           // [4096] (b_ih + b_hh)
        unsigned short* __restrict__ hall,        // [1025][32][1024] bf16 (slot 0 pre-zeroed)
        unsigned int* __restrict__ flags)         // [1025][128][4] (pre-zeroed)
{
    extern __shared__ char smem[];
    unsigned short* Wlds    = (unsigned short*)smem;                 // 98304 B
    float*          scratch = (float*)(smem + 98304);                // 8*1024 f32 = 32768 B
    float*          biasl   = (float*)(smem + 98304 + 32768);        // 128 B
    unsigned short* hstage  = (unsigned short*)(smem + 98304 + 32768 + 128); // 512 B

    const int tid  = threadIdx.x;
    const int wg   = blockIdx.x;
    const int lane = tid & 63;
    const int wq   = tid >> 6;
    const int l15  = lane & 15;
    const int l4   = lane >> 4;

    // ---- one-time: stage W slice into LDS (swizzled) ----
    for (int s = tid; s < 32 * 192; s += 512) {
        int col = s / 192, g = s % 192;
        int grow = (col >> 3) * H_ + wg * 8 + (col & 7);
        const unsigned short* src = (g < 128) ? (whh + grow * H_ + g * 8)
                                              : (wih + grow * I_ + (g - 128) * 8);
        int4 v = *(const int4*)src;
        int gd = g ^ (col & 7);
        *(int4*)(Wlds + col * 1536 + gd * 8) = v;
    }
    if (tid < 32)
        biasl[tid] = bias[(tid >> 3) * H_ + wg * 8 + (tid & 7)];
    __syncthreads();

    float c_state = 0.0f;
    float* myscr = scratch + wq * 1024;

    for (int t = 0; t < T_; ++t) {
        f32x4 acc[2][2];
        #pragma unroll
        for (int a = 0; a < 2; a++)
            #pragma unroll
            for (int b = 0; b < 2; b++) acc[a][b] = (f32x4){0.f, 0.f, 0.f, 0.f};

        // ---- x-part first (no h dependency; overlaps flag propagation) ----
        #pragma unroll
        for (int kxs = 0; kxs < 2; kxs++) {
            int kk = wq * 64 + kxs * 32 + l4 * 8;
            bf16x8 af[2];
            #pragma unroll
            for (int mt = 0; mt < 2; mt++) {
                int bb = mt * 16 + l15;
                af[mt] = *(const bf16x8*)(xb + ((size_t)t * B_ + bb) * I_ + kk);
            }
            int gbase = 128 + (kk >> 3);
            bf16x8 bfr[2];
            #pragma unroll
            for (int nt = 0; nt < 2; nt++) {
                int col = nt * 16 + l15;
                int gg = gbase ^ (col & 7);
                bfr[nt] = *(const bf16x8*)(Wlds + col * 1536 + gg * 8);
            }
            #pragma unroll
            for (int mt = 0; mt < 2; mt++)
                #pragma unroll
                for (int nt = 0; nt < 2; nt++)
                    acc[mt][nt] = __builtin_amdgcn_mfma_f32_16x16x32_bf16(af[mt], bfr[nt], acc[mt][nt], 0, 0, 0);
        }

        // ---- per-wave wait: 64 producer flags for this wave's h K-slice ----
        if (t > 0) {
            const u64* fp = (const u64*)(flags + (size_t)t * 512 + wq * 64);
            if (lane < 32) {
                const u64* p = fp + lane;
                while (__hip_atomic_load(p, __ATOMIC_RELAXED, __HIP_MEMORY_SCOPE_AGENT)
                       != 0x0000000100000001ULL)
                    __builtin_amdgcn_s_sleep(1);
            }
            asm volatile("" ::: "memory");
        }

        // ---- h-part ----
        const unsigned short* hprev = hall + (size_t)t * (B_ * H_);
        #pragma unroll
        for (int khs = 0; khs < 4; khs++) {
            int kk = wq * 128 + khs * 32 + l4 * 8;
            bf16x8 af[2];
            #pragma unroll
            for (int mt = 0; mt < 2; mt++) {
                int bb = mt * 16 + l15;
                af[mt] = *(const bf16x8*)(hprev + bb * H_ + kk);
            }
            int gbase = kk >> 3;
            bf16x8 bfr[2];
            #pragma unroll
            for (int nt = 0; nt < 2; nt++) {
                int col = nt * 16 + l15;
                int gg = gbase ^ (col & 7);
                bfr[nt] = *(const bf16x8*)(Wlds + col * 1536 + gg * 8);
            }
            #pragma unroll
            for (int mt = 0; mt < 2; mt++)
                #pragma unroll
                for (int nt = 0; nt < 2; nt++)
                    acc[mt][nt] = __builtin_amdgcn_mfma_f32_16x16x32_bf16(af[mt], bfr[nt], acc[mt][nt], 0, 0, 0);
        }

        // ---- partials -> per-wave scratch region (swizzled plain writes) ----
        #pragma unroll
        for (int mt = 0; mt < 2; mt++)
            #pragma unroll
            for (int nt = 0; nt < 2; nt++)
                #pragma unroll
                for (int r = 0; r < 4; r++) {
                    int bb  = mt * 16 + l4 * 4 + r;
                    int col = nt * 16 + l15;
                    myscr[bb * 32 + (col ^ ((bb & 7) << 2))] = acc[mt][nt][r];
                }
        __syncthreads();   // the ONLY barrier per step

        // ---- pointwise + publish (waves 0-3); waves 4-7 run ahead ----
        if (tid < 256) {
            int bb = tid >> 3, u = tid & 7;
            int sw = (bb & 7) << 2;
            float p0 = biasl[u], p1 = biasl[8 + u], p2 = biasl[16 + u], p3 = biasl[24 + u];
            #pragma unroll
            for (int q = 0; q < 8; q++) {
                const float* sc = scratch + q * 1024 + bb * 32;
                p0 += sc[(u)      ^ sw];
                p1 += sc[(8 + u)  ^ sw];
                p2 += sc[(16 + u) ^ sw];
                p3 += sc[(24 + u) ^ sw];
            }
            float ig = sigf(p0), fg = sigf(p1), gg = tanh_f(p2), og = sigf(p3);
            c_state = fg * c_state + ig * gg;
            float h = og * tanh_f(c_state);
            hstage[bb * 8 + u] = f2bf(h);            // wave-private region
            asm volatile("s_waitcnt lgkmcnt(0)" ::: "memory");

            int w = tid >> 6, i = tid & 63;
            if (i < 16) {
                int pb = w * 8 + (i >> 1), part = i & 1;
                u64 q = *(const u64*)(hstage + pb * 8 + part * 4);
                u64* dst = (u64*)(hall + ((size_t)(t + 1) * B_ + pb) * H_ + wg * 8 + part * 4);
                __hip_atomic_store(dst, q, __ATOMIC_RELAXED, __HIP_MEMORY_SCOPE_AGENT);
            }
            asm volatile("s_waitcnt vmcnt(0)" ::: "memory");
            if (i == 0)
                __hip_atomic_store(flags + (size_t)(t + 1) * 512 + wg * 4 + w, 1u,
                                   __ATOMIC_RELAXED, __HIP_MEMORY_SCOPE_AGENT);
        }
    }
}

// ---------------- output GEMMs: C[M x N] = A[M x 1024] * B[N x 1024]^T + bias ----------------
template<int PERM>
__global__ __launch_bounds__(256) void gemm_bt(
        const unsigned short* __restrict__ A,
        const unsigned short* __restrict__ Bw,
        const float* __restrict__ bias,
        float* __restrict__ out)
{
    __shared__ unsigned short As[128 * 64];
    __shared__ unsigned short Bs[128 * 64];
    const int tid  = threadIdx.x;
    const int lane = tid & 63, w = tid >> 6;
    const int wm = w >> 1, wn = w & 1;
    const int mbase = blockIdx.y * 128, nbase = blockIdx.x * 128;
    const int l15 = lane & 15, l4 = lane >> 4;

    f32x4 acc[4][4];
    #pragma unroll
    for (int i = 0; i < 4; i++)
        #pragma unroll
        for (int j = 0; j < 4; j++) acc[i][j] = (f32x4){0.f, 0.f, 0.f, 0.f};

    for (int kb = 0; kb < 16; kb++) {
        __syncthreads();
        #pragma unroll
        for (int i = 0; i < 4; i++) {
            int s = i * 256 + tid;
            int row = s >> 3, g = s & 7;
            int gd = g ^ (row & 7);
            int4 va = *(const int4*)(A  + (mbase + row) * 1024 + kb * 64 + g * 8);
            *(int4*)(As + row * 64 + gd * 8) = va;
            int4 vb = *(const int4*)(Bw + (nbase + row) * 1024 + kb * 64 + g * 8);
            *(int4*)(Bs + row * 64 + gd * 8) = vb;
        }
        __syncthreads();
        #pragma unroll
        for (int kk = 0; kk < 2; kk++) {
            bf16x8 af[4], bf[4];
            #pragma unroll
            for (int mt = 0; mt < 4; mt++) {
                int row = wm * 64 + mt * 16 + l15;
                int gg = (kk * 4 + l4) ^ (row & 7);
                af[mt] = *(const bf16x8*)(As + row * 64 + gg * 8);
            }
            #pragma unroll
            for (int nt = 0; nt < 4; nt++) {
                int row = wn * 64 + nt * 16 + l15;
                int gg = (kk * 4 + l4) ^ (row & 7);
                bf[nt] = *(const bf16x8*)(Bs + row * 64 + gg * 8);
            }
            #pragma unroll
            for (int mt = 0; mt < 4; mt++)
                #pragma unroll
                for (int nt = 0; nt < 4; nt++)
                    acc[mt][nt] = __builtin_amdgcn_mfma_f32_16x16x32_bf16(af[mt], bf[nt], acc[mt][nt], 0, 0, 0);
        }
    }
    #pragma unroll
    for (int mt = 0; mt < 4; mt++)
        #pragma unroll
        for (int nt = 0; nt < 4; nt++)
            #pragma unroll
            for (int r = 0; r < 4; r++) {
                int grow = mbase + wm * 64 + mt * 16 + l4 * 4 + r;
                int gcol = nbase + wn * 64 + nt * 16 + l15;
                float v = acc[mt][nt][r] + bias[gcol];
                int idx;
                if (PERM == 1) {
                    int tt = grow >> 5, bb = grow & 31;
                    idx = (bb * 1024 + tt) * 512 + gcol;
                } else {
                    idx = grow * 1024 + gcol;
                }
                out[idx] = v;
            }
}

// ---------------- host ----------------
extern "C" void kernel_launch(void* const* d_in, const int* in_sizes, int n_in,
                              void* d_out, int out_size, void* d_ws, size_t ws_size,
                              hipStream_t stream) {
    (void)in_sizes; (void)n_in; (void)out_size; (void)ws_size;
    const float* x    = (const float*)d_in[0];
    const float* Wih  = (const float*)d_in[1];
    const float* Whh  = (const float*)d_in[2];
    const float* bih  = (const float*)d_in[3];
    const float* bhh  = (const float*)d_in[4];
    const float* fcw  = (const float*)d_in[5];
    const float* fcb  = (const float*)d_in[6];
    const float* lnw  = (const float*)d_in[7];
    const float* lnb  = (const float*)d_in[8];
    float* out = (float*)d_out;

    char* ws = (char*)d_ws;
    size_t o = 0;
    unsigned short* whh_b = (unsigned short*)(ws + o); o += 8388608;   // [4096][1024]
    unsigned short* wih_b = (unsigned short*)(ws + o); o += 4194304;   // [4096][512]
    unsigned short* fcw_b = (unsigned short*)(ws + o); o += 1048576;   // [512][1024]
    unsigned short* lnw_b = (unsigned short*)(ws + o); o += 2097152;   // [1024][1024]
    unsigned short* x_b   = (unsigned short*)(ws + o); o += 33554432;  // [1024][32][512]
    float*          bias_c = (float*)(ws + o);         o += 16384;     // [4096]
    unsigned short* hall  = (unsigned short*)(ws + o); o += 67174400;  // [1025][32][1024]
    unsigned int*   flags = (unsigned int*)(ws + o);   o += 2099200;   // [1025][128][4]

    hipMemsetAsync(flags, 0, 2099200, stream);
    hipMemsetAsync(hall, 0, 65536, stream);      // h slot 0 = zeros

    cvt_kernel<<<4096,  256, 0, stream>>>(Whh, whh_b, 4194304 / 4);
    cvt_kernel<<<2048,  256, 0, stream>>>(Wih, wih_b, 2097152 / 4);
    cvt_kernel<<<512,   256, 0, stream>>>(fcw, fcw_b, 524288 / 4);
    cvt_kernel<<<1024,  256, 0, stream>>>(lnw, lnw_b, 1048576 / 4);
    cvt_x_kernel<<<16384, 256, 0, stream>>>(x, x_b);
    bias_kernel<<<16, 256, 0, stream>>>(bih, bhh, bias_c);

    const unsigned short* a0 = whh_b;
    const unsigned short* a1 = wih_b;
    const unsigned short* a2 = x_b;
    const float*          a3 = bias_c;
    unsigned short*       a4 = hall;
    unsigned int*         a5 = flags;
    void* args[6] = { (void*)&a0, (void*)&a1, (void*)&a2, (void*)&a3, (void*)&a4, (void*)&a5 };
    hipLaunchCooperativeKernel((void*)lstm_rec, dim3(NWG), dim3(512), args,
                               (unsigned)(98304 + 32768 + 128 + 512), stream);

    const unsigned short* hseq = hall + 32768;  // slot 1 = h at t=0
    gemm_bt<1><<<dim3(4, 256), 256, 0, stream>>>(hseq, fcw_b, fcb, out);
    gemm_bt<2><<<dim3(8, 256), 256, 0, stream>>>(hseq, lnw_b, lnb, out + 16777216);
}